// Round 4
// baseline (1646.473 us; speedup 1.0000x reference)
//
#include <hip/hip_runtime.h>
#include <hip/hip_bf16.h>
#include <math.h>

// MistralAttention_offloading. R4: kill top-256 selection flips.
// (a) Q/K projections via SPLIT-PRECISION bf16 MFMA (hi+lo, 3 passes) -> q,k
//     accurate to ~1e-6 rel even when inputs are fp32 (bf16 inputs: lo==0,
//     passes skipped at runtime).
// (b) RoPE inv_freq computed in double then rounded to fp32; angle = fp32
//     pos*inv (replicates reference rounding chain); accurate sinf/cosf.
// Runtime input-dtype detection kept (attention_mask ushort[1]).
// Selection itself is exact + stable-tie (matches jnp stable argsort).

typedef __hip_bfloat16 bf16;
typedef unsigned short ushort_t;
typedef __attribute__((ext_vector_type(8))) short short8;
typedef __attribute__((ext_vector_type(4))) float f32x4;

#define QL   1024
#define DM   4096
#define NH   32
#define NKV  8
#define HD   128
#define GRP  4      // NH/NKV
#define OUTL 16     // HD/GROUP_FACTOR
#define HC   256    // HEAVY_CONST
#define MNEG (-1.0e30f)

// order-preserving float -> uint map (descending float order == descending uint)
__device__ __forceinline__ unsigned mapf(float f) {
  unsigned u = __float_as_uint(f);
  return (u & 0x80000000u) ? ~u : (u | 0x80000000u);
}

// round-to-nearest-even fp32 -> bf16 bits
__device__ __forceinline__ unsigned short f2bf(float x) {
  unsigned u = __float_as_uint(x);
  unsigned r = (u + 0x7FFFu + ((u >> 16) & 1u)) >> 16;
  return (unsigned short)r;
}
__device__ __forceinline__ float bf2f(unsigned short h) {
  return __uint_as_float(((unsigned)h) << 16);
}

__device__ __forceinline__ short8 cvt8(const float* p) {
  f32x4 a = *(const f32x4*)p;
  f32x4 b = *(const f32x4*)(p + 4);
  short8 r;
#pragma unroll
  for (int i = 0; i < 4; i++) r[i] = (short)f2bf(a[i]);
#pragma unroll
  for (int i = 0; i < 4; i++) r[4 + i] = (short)f2bf(b[i]);
  return r;
}

// split fp32x8 -> bf16 hi + bf16 residual lo
__device__ __forceinline__ void split8(const float* p, short8& h, short8& l) {
  f32x4 a = *(const f32x4*)p;
  f32x4 b = *(const f32x4*)(p + 4);
#pragma unroll
  for (int i = 0; i < 4; i++) {
    unsigned short hh = f2bf(a[i]);
    h[i] = (short)hh;
    l[i] = (short)f2bf(a[i] - bf2f(hh));
  }
#pragma unroll
  for (int i = 0; i < 4; i++) {
    unsigned short hh = f2bf(b[i]);
    h[4 + i] = (short)hh;
    l[4 + i] = (short)f2bf(b[i] - bf2f(hh));
  }
}

// ---------------------------------------------------------------------------
// Transpose bf16: src K x N (row-major) -> dst N x K. 64x64 tiles, XOR swizzle.
__global__ __launch_bounds__(256)
void transpose_bf16_kernel(const bf16* __restrict__ src, bf16* __restrict__ dst,
                           int K, int N, long long srcBS, long long dstBS) {
  __shared__ alignas(16) unsigned short tile[64][64];
  const bf16* s = src + (size_t)blockIdx.z * srcBS;
  bf16* d = dst + (size_t)blockIdx.z * dstBS;
  const int k0 = blockIdx.y * 64, n0 = blockIdx.x * 64;
  const int t = threadIdx.x;
  {
    const int r = t >> 3;
    const int c8 = (t & 7) * 8;
    const int sw0 = ((r >> 3) & 7) * 8;
    const int sw1 = (((r + 32) >> 3) & 7) * 8;
    *(short8*)&tile[r][c8 ^ sw0] =
        *(const short8*)&s[(size_t)(k0 + r) * N + n0 + c8];
    *(short8*)&tile[r + 32][c8 ^ sw1] =
        *(const short8*)&s[(size_t)(k0 + r + 32) * N + n0 + c8];
  }
  __syncthreads();
  {
    const int kc8 = t & 7;
    const int nr = t >> 3;
    short8 v0, v1;
#pragma unroll
    for (int j = 0; j < 8; j++) {
      const int rowj = kc8 * 8 + j;
      const int swj = ((rowj >> 3) & 7) * 8;
      v0[j] = (short)tile[rowj][nr ^ swj];
      v1[j] = (short)tile[rowj][(nr + 32) ^ swj];
    }
    *(short8*)&d[(size_t)(n0 + nr) * K + k0 + kc8 * 8] = v0;
    *(short8*)&d[(size_t)(n0 + nr + 32) * K + k0 + kc8 * 8] = v1;
  }
}

// ---------------------------------------------------------------------------
// Split-precision GEMM for Q/K projections. C(fp32)[m][coff+n] = A[m][k]B[k][n].
// fp32 inputs: 3 MFMA passes (AhBh + AhBl + AlBh). bf16 inputs: 1 pass.
__global__ __launch_bounds__(256)
void gemm_qk_kernel(const void* __restrict__ Av, const void* __restrict__ Bv,
                    float* __restrict__ C, const ushort_t* __restrict__ msk,
                    int N, int K, int ldc, int coff) {
  const bool ibf = (msk[1] != 0);
  __shared__ alignas(16) bf16 sAh[128 * 32];
  __shared__ alignas(16) bf16 sAl[128 * 32];
  __shared__ alignas(16) bf16 sBh[128 * 32];   // [n][k]
  __shared__ alignas(16) bf16 sBl[128 * 32];
  const int m0 = blockIdx.y * 128, n0 = blockIdx.x * 128;
  const int t = threadIdx.x, lane = t & 63, wave = t >> 6;
  const int wm = (wave >> 1) * 64, wn = (wave & 1) * 64;
  const int mrow = lane & 15, kq = (lane >> 4) * 8;
  const int r0 = t >> 2, o0 = (t & 3) * 8;
  const int bk2 = (t >> 4) * 2;
  const int bn8 = (t & 15) * 8;
  f32x4 acc[4][4];
#pragma unroll
  for (int i = 0; i < 4; i++)
#pragma unroll
    for (int j = 0; j < 4; j++) acc[i][j] = (f32x4){0.f, 0.f, 0.f, 0.f};

  for (int kk = 0; kk < K; kk += 32) {
    short8 ah0, al0, ah1, al1, bh0, bl0, bh1, bl1;
    if (ibf) {
      const bf16* A = (const bf16*)Av;
      const bf16* B = (const bf16*)Bv;
      ah0 = *(const short8*)&A[(size_t)(m0 + r0) * K + kk + o0];
      ah1 = *(const short8*)&A[(size_t)(m0 + r0 + 64) * K + kk + o0];
      bh0 = *(const short8*)&B[(size_t)(kk + bk2) * N + n0 + bn8];
      bh1 = *(const short8*)&B[(size_t)(kk + bk2 + 1) * N + n0 + bn8];
    } else {
      const float* A = (const float*)Av;
      const float* B = (const float*)Bv;
      split8(&A[(size_t)(m0 + r0) * K + kk + o0], ah0, al0);
      split8(&A[(size_t)(m0 + r0 + 64) * K + kk + o0], ah1, al1);
      split8(&B[(size_t)(kk + bk2) * N + n0 + bn8], bh0, bl0);
      split8(&B[(size_t)(kk + bk2 + 1) * N + n0 + bn8], bh1, bl1);
    }
    __syncthreads();
    *(short8*)&sAh[r0 * 32 + o0] = ah0;
    *(short8*)&sAh[(r0 + 64) * 32 + o0] = ah1;
#pragma unroll
    for (int i = 0; i < 8; i++) {
      unsigned pv = (unsigned)(unsigned short)bh0[i] |
                    ((unsigned)(unsigned short)bh1[i] << 16);
      *(unsigned*)&sBh[(bn8 + i) * 32 + bk2] = pv;
    }
    if (!ibf) {
      *(short8*)&sAl[r0 * 32 + o0] = al0;
      *(short8*)&sAl[(r0 + 64) * 32 + o0] = al1;
#pragma unroll
      for (int i = 0; i < 8; i++) {
        unsigned pv = (unsigned)(unsigned short)bl0[i] |
                      ((unsigned)(unsigned short)bl1[i] << 16);
        *(unsigned*)&sBl[(bn8 + i) * 32 + bk2] = pv;
      }
    }
    __syncthreads();
    short8 afh[4], bfh[4];
#pragma unroll
    for (int i = 0; i < 4; i++)
      afh[i] = *(const short8*)&sAh[(wm + i * 16 + mrow) * 32 + kq];
#pragma unroll
    for (int j = 0; j < 4; j++)
      bfh[j] = *(const short8*)&sBh[(wn + j * 16 + mrow) * 32 + kq];
#pragma unroll
    for (int i = 0; i < 4; i++)
#pragma unroll
      for (int j = 0; j < 4; j++)
        acc[i][j] = __builtin_amdgcn_mfma_f32_16x16x32_bf16(afh[i], bfh[j], acc[i][j], 0, 0, 0);
    if (!ibf) {
      short8 afl[4], bfl[4];
#pragma unroll
      for (int i = 0; i < 4; i++)
        afl[i] = *(const short8*)&sAl[(wm + i * 16 + mrow) * 32 + kq];
#pragma unroll
      for (int j = 0; j < 4; j++)
        bfl[j] = *(const short8*)&sBl[(wn + j * 16 + mrow) * 32 + kq];
#pragma unroll
      for (int i = 0; i < 4; i++)
#pragma unroll
        for (int j = 0; j < 4; j++)
          acc[i][j] = __builtin_amdgcn_mfma_f32_16x16x32_bf16(afh[i], bfl[j], acc[i][j], 0, 0, 0);
#pragma unroll
      for (int i = 0; i < 4; i++)
#pragma unroll
        for (int j = 0; j < 4; j++)
          acc[i][j] = __builtin_amdgcn_mfma_f32_16x16x32_bf16(afl[i], bfh[j], acc[i][j], 0, 0, 0);
    }
  }
  const int rq = (lane >> 4) * 4, cn = lane & 15;
#pragma unroll
  for (int i = 0; i < 4; i++)
#pragma unroll
    for (int r = 0; r < 4; r++) {
      const size_t rowi = (size_t)(m0 + wm + i * 16 + rq + r);
#pragma unroll
      for (int j = 0; j < 4; j++)
        C[rowi * ldc + (coff + n0 + wn + j * 16 + cn)] = acc[i][j][r];
    }
}

// ---------------------------------------------------------------------------
// Plain bf16 GEMM (V projection, Wo). dtypes resolved at runtime.
// aDt: 1=force bf16. outMode: 0=fp32, 2=bf16-if-detected-bf16.
__global__ __launch_bounds__(256)
void gemm_nn_kernel(const void* __restrict__ Av, const void* __restrict__ Bv,
                    void* __restrict__ Cv, const ushort_t* __restrict__ msk,
                    int N, int K, int ldc, int coff, int aDt, int outMode) {
  const bool ibf = (msk[1] != 0);
  const bool aBf = (aDt == 1) || ibf;
  const bool oBf = (outMode == 2) && ibf;
  __shared__ alignas(16) bf16 sA[128 * 32];
  __shared__ alignas(16) bf16 sB[128 * 32];
  const int m0 = blockIdx.y * 128, n0 = blockIdx.x * 128;
  const int t = threadIdx.x, lane = t & 63, wave = t >> 6;
  const int wm = (wave >> 1) * 64, wn = (wave & 1) * 64;
  const int mrow = lane & 15, kq = (lane >> 4) * 8;
  const int r0 = t >> 2, o0 = (t & 3) * 8;
  const int bk2 = (t >> 4) * 2;
  const int bn8 = (t & 15) * 8;
  f32x4 acc[4][4];
#pragma unroll
  for (int i = 0; i < 4; i++)
#pragma unroll
    for (int j = 0; j < 4; j++) acc[i][j] = (f32x4){0.f, 0.f, 0.f, 0.f};

  for (int kk = 0; kk < K; kk += 32) {
    short8 av0, av1, bv0, bv1;
    if (aBf) {
      const bf16* A = (const bf16*)Av;
      av0 = *(const short8*)&A[(size_t)(m0 + r0) * K + kk + o0];
      av1 = *(const short8*)&A[(size_t)(m0 + r0 + 64) * K + kk + o0];
    } else {
      const float* A = (const float*)Av;
      av0 = cvt8(&A[(size_t)(m0 + r0) * K + kk + o0]);
      av1 = cvt8(&A[(size_t)(m0 + r0 + 64) * K + kk + o0]);
    }
    if (ibf) {
      const bf16* B = (const bf16*)Bv;
      bv0 = *(const short8*)&B[(size_t)(kk + bk2) * N + n0 + bn8];
      bv1 = *(const short8*)&B[(size_t)(kk + bk2 + 1) * N + n0 + bn8];
    } else {
      const float* B = (const float*)Bv;
      bv0 = cvt8(&B[(size_t)(kk + bk2) * N + n0 + bn8]);
      bv1 = cvt8(&B[(size_t)(kk + bk2 + 1) * N + n0 + bn8]);
    }
    __syncthreads();
    *(short8*)&sA[r0 * 32 + o0] = av0;
    *(short8*)&sA[(r0 + 64) * 32 + o0] = av1;
#pragma unroll
    for (int i = 0; i < 8; i++) {
      unsigned pv = (unsigned)(unsigned short)bv0[i] |
                    ((unsigned)(unsigned short)bv1[i] << 16);
      *(unsigned*)&sB[(bn8 + i) * 32 + bk2] = pv;
    }
    __syncthreads();
    short8 af[4], bfr[4];
#pragma unroll
    for (int i = 0; i < 4; i++)
      af[i] = *(const short8*)&sA[(wm + i * 16 + mrow) * 32 + kq];
#pragma unroll
    for (int j = 0; j < 4; j++)
      bfr[j] = *(const short8*)&sB[(wn + j * 16 + mrow) * 32 + kq];
#pragma unroll
    for (int i = 0; i < 4; i++)
#pragma unroll
      for (int j = 0; j < 4; j++)
        acc[i][j] = __builtin_amdgcn_mfma_f32_16x16x32_bf16(af[i], bfr[j], acc[i][j], 0, 0, 0);
  }
  const int rq = (lane >> 4) * 4, cn = lane & 15;
#pragma unroll
  for (int i = 0; i < 4; i++)
#pragma unroll
    for (int r = 0; r < 4; r++) {
      const size_t rowi = (size_t)(m0 + wm + i * 16 + rq + r);
#pragma unroll
      for (int j = 0; j < 4; j++) {
        const size_t idx = rowi * ldc + (coff + n0 + wn + j * 16 + cn);
        if (oBf)
          ((bf16*)Cv)[idx] = __float2bfloat16(acc[i][j][r]);
        else
          ((float*)Cv)[idx] = acc[i][j][r];
      }
    }
}

// ---------------------------------------------------------------------------
// RoPE for q + gq quantization. block=(128 threads)=one (h,pos).
__global__ __launch_bounds__(128)
void rope_q_gq_kernel(const float* __restrict__ qkv, const int* __restrict__ sc,
                      bf16* __restrict__ qr, float* __restrict__ gq) {
  const int pos = blockIdx.x, h = blockIdx.y, d = threadIdx.x;
  __shared__ float sv[HD], sr[HD];
  __shared__ float smn, smx;
  float v = qkv[(size_t)pos * 6144 + h * HD + d];
  sv[d] = v;
  __syncthreads();
  const int fi = d & 63;
  // inv_freq: correctly-rounded fp32 via double pow; angle in fp32 (matches ref chain)
  float inv = (float)(1.0 / pow(10000.0, (double)fi * (1.0 / 64.0)));
  float ang = (float)pos * inv;
  float c = cosf(ang), s = sinf(ang);
  float rot = (d < 64) ? -sv[d + 64] : sv[d - 64];
  float r = v * c + rot * s;
  sr[d] = r;
  qr[((size_t)h * QL + pos) * HD + d] = __float2bfloat16(r);
  __syncthreads();
  if (d == 0) {
    float mn = 3.4e38f, mx = -3.4e38f;
    for (int j = 0; j < OUTL; j++) {
      float g = sr[sc[h * HD + j]];
      mn = fminf(mn, g);
      mx = fmaxf(mx, g);
    }
    smn = mn; smx = mx;
  }
  __syncthreads();
  if (d < OUTL) {
    float g = sr[sc[h * HD + d]];
    float rng = smx - smn;
    if (rng == 0.f) rng = 1.f;
    float scale = 15.0f / rng;
    float qv = rintf((g - smn) * scale);
    qv = fminf(fmaxf(qv, 0.f), 15.f);
    gq[((size_t)h * QL + pos) * OUTL + d] = qv / scale + smn;
  }
}

// RoPE for k + gk quantization (per query-head) + v row cast.
__global__ __launch_bounds__(128)
void rope_k_gk_kernel(const float* __restrict__ qkv, const int* __restrict__ sc,
                      bf16* __restrict__ kr, bf16* __restrict__ vrow,
                      float* __restrict__ gk) {
  const int pos = blockIdx.x, kvh = blockIdx.y, d = threadIdx.x;
  __shared__ float sv[HD], sr[HD];
  __shared__ float smn[GRP], smx[GRP];
  float kv = qkv[(size_t)pos * 6144 + DM + kvh * HD + d];
  float vv = qkv[(size_t)pos * 6144 + DM + NKV * HD + kvh * HD + d];
  sv[d] = kv;
  __syncthreads();
  const int fi = d & 63;
  float inv = (float)(1.0 / pow(10000.0, (double)fi * (1.0 / 64.0)));
  float ang = (float)pos * inv;
  float c = cosf(ang), s = sinf(ang);
  float rot = (d < 64) ? -sv[d + 64] : sv[d - 64];
  float r = kv * c + rot * s;
  sr[d] = r;
  kr[((size_t)kvh * QL + pos) * HD + d] = __float2bfloat16(r);
  vrow[((size_t)kvh * QL + pos) * HD + d] = __float2bfloat16(vv);
  __syncthreads();
  if (d < 64 && (d & 15) == 0) {
    const int g = d >> 4;
    const int h = kvh * GRP + g;
    float mn = 3.4e38f, mx = -3.4e38f;
    for (int j = 0; j < OUTL; j++) {
      float x = sr[sc[h * HD + j]];
      mn = fminf(mn, x);
      mx = fmaxf(mx, x);
    }
    smn[g] = mn; smx[g] = mx;
  }
  __syncthreads();
  if (d < 64) {
    const int g = d >> 4, j = d & 15;
    const int h = kvh * GRP + g;
    float x = sr[sc[h * HD + j]];
    float rng = smx[g] - smn[g];
    if (rng == 0.f) rng = 1.f;
    float scale = 15.0f / rng;
    float qv = rintf((x - smn[g]) * scale);
    qv = fminf(fmaxf(qv, 0.f), 15.f);
    gk[((size_t)h * QL + pos) * OUTL + j] = qv / scale + smn[g];
  }
}

// ---------------------------------------------------------------------------
// Fused attention: one block = (head h, 8 queries). 256 threads = 4 waves.
__global__ __launch_bounds__(256)
void attn_kernel(const bf16* __restrict__ qr, const bf16* __restrict__ kr,
                 const bf16* __restrict__ vT, const float* __restrict__ gq,
                 const float* __restrict__ gk, bf16* __restrict__ ao) {
  const int h = blockIdx.y;
  const int q0 = blockIdx.x * 8;
  const int kvh = h >> 2;
  const int t = threadIdx.x;
  const int lane = t & 63, wave = t >> 6;
  const int mrow = lane & 15, kq = (lane >> 4) * 8;

  __shared__ alignas(16) bf16 sQ[16][HD];
  __shared__ float sGq[8][OUTL];
  __shared__ alignas(16) float sBuf[8][QL];
  __shared__ float sL[8];

  {
    const int r = t >> 4, c = (t & 15) * 8;
    short8 z = {0, 0, 0, 0, 0, 0, 0, 0};
    if (r < 8)
      *(short8*)&sQ[r][c] = *(const short8*)&qr[((size_t)h * QL + q0 + r) * HD + c];
    else
      *(short8*)&sQ[r][c] = z;
    if (t < 128)
      sGq[t >> 4][t & 15] = gq[((size_t)h * QL + q0 + (t >> 4)) * OUTL + (t & 15)];
  }
  __syncthreads();

  // ---- gattn (fp32, exact path for selection)
  for (int kk = t; kk < QL; kk += 256) {
    const float* gkp = &gk[((size_t)h * QL + kk) * OUTL];
    float gv[OUTL];
#pragma unroll
    for (int j = 0; j < OUTL; j++) gv[j] = gkp[j];
#pragma unroll
    for (int r = 0; r < 8; r++) {
      float s = 0.f;
#pragma unroll
      for (int j = 0; j < OUTL; j++) s += sGq[r][j] * gv[j];
      sBuf[r][kk] = (kk <= q0 + r) ? s * 0.25f : MNEG;
    }
  }
  __syncthreads();

  // ---- exact top-256 selection per row (stable-tie semantics)
  const int row = t >> 5, j32 = t & 31;
  unsigned sel;
  {
    unsigned uv[32];
#pragma unroll
    for (int kk = 0; kk < 32; kk++) uv[kk] = mapf(sBuf[row][j32 * 32 + kk]);
    unsigned T = 0u;
    for (int b = 31; b >= 0; b--) {
      unsigned Tc = T | (1u << b);
      int c = 0;
#pragma unroll
      for (int kk = 0; kk < 32; kk++) c += (uv[kk] >= Tc) ? 1 : 0;
      c += __shfl_xor(c, 1, 32);
      c += __shfl_xor(c, 2, 32);
      c += __shfl_xor(c, 4, 32);
      c += __shfl_xor(c, 8, 32);
      c += __shfl_xor(c, 16, 32);
      if (c >= HC) T = Tc;
    }
    unsigned gtm = 0u, eqm = 0u;
    int cgt = 0;
#pragma unroll
    for (int kk = 0; kk < 32; kk++) {
      unsigned u = uv[kk];
      if (u > T) { gtm |= (1u << kk); cgt++; }
      else if (u == T) eqm |= (1u << kk);
    }
    int cg = cgt;
    cg += __shfl_xor(cg, 1, 32);
    cg += __shfl_xor(cg, 2, 32);
    cg += __shfl_xor(cg, 4, 32);
    cg += __shfl_xor(cg, 8, 32);
    cg += __shfl_xor(cg, 16, 32);
    const int needEq = HC - cg;
    int eqc = __popc(eqm);
    int pre = eqc;
    for (int dlt = 1; dlt < 32; dlt <<= 1) {
      int o = __shfl_up(pre, dlt, 32);
      if (j32 >= dlt) pre += o;
    }
    pre -= eqc;
    int take = needEq - pre;
    unsigned mm = eqm;
    sel = gtm;
    for (int i = 0; i < take && mm != 0u; i++) {
      unsigned b = mm & (0u - mm);
      sel |= b;
      mm ^= b;
    }
  }
  __syncthreads();

  // ---- QK^T via MFMA (causal mask applied on store)
  {
    short8 aq[4];
#pragma unroll
    for (int kb = 0; kb < 4; kb++)
      aq[kb] = *(const short8*)&sQ[mrow][kb * 32 + kq];
    const bf16* krh = &kr[(size_t)kvh * QL * HD];
    for (int nt = wave; nt < 64; nt += 4) {
      const int kb0 = nt * 16;
      f32x4 acc = {0.f, 0.f, 0.f, 0.f};
#pragma unroll
      for (int kb = 0; kb < 4; kb++) {
        short8 bfr = *(const short8*)&krh[(size_t)(kb0 + mrow) * HD + kb * 32 + kq];
        acc = __builtin_amdgcn_mfma_f32_16x16x32_bf16(aq[kb], bfr, acc, 0, 0, 0);
      }
      const int key = kb0 + mrow;
#pragma unroll
      for (int r = 0; r < 4; r++) {
        const int m = (lane >> 4) * 4 + r;
        if (m < 8) {
          float v = acc[r] * 0.08838834764831845f;  // 1/sqrt(128)
          sBuf[m][key] = (key <= q0 + m) ? v : MNEG;
        }
      }
    }
  }
  __syncthreads();

  // ---- masked softmax; write p as bf16 overlay at sBuf base
  {
    float av[32];
    float mx = MNEG;
#pragma unroll
    for (int kk = 0; kk < 32; kk++) {
      av[kk] = sBuf[row][j32 * 32 + kk];
      if (sel & (1u << kk)) mx = fmaxf(mx, av[kk]);
    }
    mx = fmaxf(mx, __shfl_xor(mx, 1, 32));
    mx = fmaxf(mx, __shfl_xor(mx, 2, 32));
    mx = fmaxf(mx, __shfl_xor(mx, 4, 32));
    mx = fmaxf(mx, __shfl_xor(mx, 8, 32));
    mx = fmaxf(mx, __shfl_xor(mx, 16, 32));
    float ls = 0.f;
#pragma unroll
    for (int kk = 0; kk < 32; kk++) {
      float p = 0.f;
      if (sel & (1u << kk)) {
        float e = av[kk] - mx;
        p = (e < -80.f) ? 0.f : expf(e);
        ls += p;
      }
      av[kk] = p;
    }
    ls += __shfl_xor(ls, 1, 32);
    ls += __shfl_xor(ls, 2, 32);
    ls += __shfl_xor(ls, 4, 32);
    ls += __shfl_xor(ls, 8, 32);
    ls += __shfl_xor(ls, 16, 32);
    if (j32 == 0) sL[row] = ls;
    __syncthreads();
    bf16* P = (bf16*)&sBuf[0][0];
#pragma unroll
    for (int kk = 0; kk < 32; kk++)
      P[(size_t)row * QL + j32 * 32 + kk] = __float2bfloat16(av[kk]);
    short8 z = {0, 0, 0, 0, 0, 0, 0, 0};
    short8* Pz = (short8*)&sBuf[4][0];   // == &P[8*QL]
#pragma unroll
    for (int i = 0; i < 4; i++) Pz[t * 4 + i] = z;
  }
  __syncthreads();

  // ---- PV via MFMA (dense over 1024 keys; unselected p == 0)
  {
    const bf16* Pb = (const bf16*)&sBuf[0][0];
    const bf16* vTh = &vT[(size_t)kvh * HD * QL];
    for (int dt = wave; dt < 8; dt += 4) {
      const int d0 = dt * 16;
      f32x4 acc = {0.f, 0.f, 0.f, 0.f};
      for (int kb = 0; kb < 32; kb++) {
        short8 af = *(const short8*)&Pb[(size_t)mrow * QL + kb * 32 + kq];
        short8 bfr = *(const short8*)&vTh[(size_t)(d0 + mrow) * QL + kb * 32 + kq];
        acc = __builtin_amdgcn_mfma_f32_16x16x32_bf16(af, bfr, acc, 0, 0, 0);
      }
#pragma unroll
      for (int r = 0; r < 4; r++) {
        const int m = (lane >> 4) * 4 + r;
        if (m < 8) {
          float outv = acc[r] / sL[m];
          ao[(size_t)(q0 + m) * DM + h * HD + d0 + mrow] = __float2bfloat16(outv);
        }
      }
    }
  }
}

// ---------------------------------------------------------------------------
extern "C" void kernel_launch(void* const* d_in, const int* in_sizes, int n_in,
                              void* d_out, int out_size, void* d_ws, size_t ws_size,
                              hipStream_t stream) {
  (void)in_sizes; (void)n_in; (void)out_size; (void)ws_size;
  const void* hs = d_in[0];
  const ushort_t* msk = (const ushort_t*)d_in[1];  // dtype discriminator
  const void* Wq = d_in[3];
  const void* Wk = d_in[4];
  const void* Wv = d_in[5];
  const void* Wo = d_in[6];
  const int* sc = (const int*)d_in[7];

  char* ws = (char*)d_ws;
  size_t off = 0;
  auto alloc = [&](size_t bytes) {
    char* p = ws + off;
    off += (bytes + 255) & ~(size_t)255;
    return p;
  };
  float* qkv = (float*)alloc((size_t)QL * 6144 * 4);   // 25.2 MB
  bf16* ao = (bf16*)qkv;                               // aliases dead qkv
  bf16* qr = (bf16*)alloc((size_t)NH * QL * HD * 2);
  bf16* kr = (bf16*)alloc((size_t)NKV * QL * HD * 2);
  bf16* vrow = (bf16*)alloc((size_t)NKV * QL * HD * 2);
  bf16* vT = (bf16*)alloc((size_t)NKV * HD * QL * 2);
  float* gq = (float*)alloc((size_t)NH * QL * OUTL * 4);
  float* gk = (float*)alloc((size_t)NH * QL * OUTL * 4);
  // total ~42 MB

  // 1. Q,K projections (split-precision), V projection (plain bf16)
  gemm_qk_kernel<<<dim3(32, 8), 256, 0, stream>>>(hs, Wq, qkv, msk, DM, DM, 6144, 0);
  gemm_qk_kernel<<<dim3(8, 8), 256, 0, stream>>>(hs, Wk, qkv, msk, 1024, DM, 6144, 4096);
  gemm_nn_kernel<<<dim3(8, 8), 256, 0, stream>>>(hs, Wv, (void*)qkv, msk,
                                                 1024, DM, 6144, 5120, 0, 0);

  // 2. RoPE + quantized-label prep
  rope_q_gq_kernel<<<dim3(QL, NH), 128, 0, stream>>>(qkv, sc, qr, gq);
  rope_k_gk_kernel<<<dim3(QL, NKV), 128, 0, stream>>>(qkv, sc, kr, vrow, gk);
  transpose_bf16_kernel<<<dim3(2, 16, NKV), 256, 0, stream>>>(
      vrow, vT, QL, HD, (long long)(QL * HD), (long long)(HD * QL));

  // 3. fused attention (writes ao over dead qkv region)
  attn_kernel<<<dim3(QL / 8, NH), 256, 0, stream>>>(qr, kr, vT, gq, gk, ao);

  // 4. output projection (out dtype follows detected input dtype)
  gemm_nn_kernel<<<dim3(32, 8), 256, 0, stream>>>(ao, Wo, d_out, msk,
                                                  DM, DM, DM, 0, 1, 2);
}

// Round 5
// 924.986 us; speedup vs baseline: 1.7800x; 1.7800x over previous
//
#include <hip/hip_runtime.h>
#include <hip/hip_bf16.h>
#include <math.h>

// MistralAttention_offloading. R5 (perf): fix GEMM occupancy + LDS conflicts.
// - QKV fused into ONE kernel, tile 64x128 -> 768 blocks (3/CU, was 1/CU).
// - Wo tile 64x128 -> 512 blocks (2/CU).
// - XOR-swizzled sB layout: staging write conflicts 16-way -> 4-way, b128
//   frag reads stay 16B-aligned.
// Numerics identical to R4 (split-precision Q/K, exact RoPE, stable top-256).

typedef __hip_bfloat16 bf16;
typedef unsigned short ushort_t;
typedef __attribute__((ext_vector_type(8))) short short8;
typedef __attribute__((ext_vector_type(4))) float f32x4;

#define QL   1024
#define DM   4096
#define NH   32
#define NKV  8
#define HD   128
#define GRP  4      // NH/NKV
#define OUTL 16     // HD/GROUP_FACTOR
#define HC   256    // HEAVY_CONST
#define MNEG (-1.0e30f)

// order-preserving float -> uint map (descending float order == descending uint)
__device__ __forceinline__ unsigned mapf(float f) {
  unsigned u = __float_as_uint(f);
  return (u & 0x80000000u) ? ~u : (u | 0x80000000u);
}

// round-to-nearest-even fp32 -> bf16 bits
__device__ __forceinline__ unsigned short f2bf(float x) {
  unsigned u = __float_as_uint(x);
  unsigned r = (u + 0x7FFFu + ((u >> 16) & 1u)) >> 16;
  return (unsigned short)r;
}
__device__ __forceinline__ float bf2f(unsigned short h) {
  return __uint_as_float(((unsigned)h) << 16);
}

__device__ __forceinline__ short8 cvt8(const float* p) {
  f32x4 a = *(const f32x4*)p;
  f32x4 b = *(const f32x4*)(p + 4);
  short8 r;
#pragma unroll
  for (int i = 0; i < 4; i++) r[i] = (short)f2bf(a[i]);
#pragma unroll
  for (int i = 0; i < 4; i++) r[4 + i] = (short)f2bf(b[i]);
  return r;
}

// split fp32x8 -> bf16 hi + bf16 residual lo
__device__ __forceinline__ void split8(const float* p, short8& h, short8& l) {
  f32x4 a = *(const f32x4*)p;
  f32x4 b = *(const f32x4*)(p + 4);
#pragma unroll
  for (int i = 0; i < 4; i++) {
    unsigned short hh = f2bf(a[i]);
    h[i] = (short)hh;
    l[i] = (short)f2bf(a[i] - bf2f(hh));
  }
#pragma unroll
  for (int i = 0; i < 4; i++) {
    unsigned short hh = f2bf(b[i]);
    h[4 + i] = (short)hh;
    l[4 + i] = (short)f2bf(b[i] - bf2f(hh));
  }
}

// swizzled sB index: row n (0..127), k (0..31). Keeps 8-runs aligned; spreads
// the transpose-staging scatter over 4 banks instead of 1.
__device__ __forceinline__ int bswz(int n, int k) {
  return n * 32 + (k ^ (((n >> 3) & 3) * 8));
}

// ---------------------------------------------------------------------------
// Transpose bf16: src K x N (row-major) -> dst N x K. 64x64 tiles, XOR swizzle.
__global__ __launch_bounds__(256)
void transpose_bf16_kernel(const bf16* __restrict__ src, bf16* __restrict__ dst,
                           int K, int N, long long srcBS, long long dstBS) {
  __shared__ alignas(16) unsigned short tile[64][64];
  const bf16* s = src + (size_t)blockIdx.z * srcBS;
  bf16* d = dst + (size_t)blockIdx.z * dstBS;
  const int k0 = blockIdx.y * 64, n0 = blockIdx.x * 64;
  const int t = threadIdx.x;
  {
    const int r = t >> 3;
    const int c8 = (t & 7) * 8;
    const int sw0 = ((r >> 3) & 7) * 8;
    const int sw1 = (((r + 32) >> 3) & 7) * 8;
    *(short8*)&tile[r][c8 ^ sw0] =
        *(const short8*)&s[(size_t)(k0 + r) * N + n0 + c8];
    *(short8*)&tile[r + 32][c8 ^ sw1] =
        *(const short8*)&s[(size_t)(k0 + r + 32) * N + n0 + c8];
  }
  __syncthreads();
  {
    const int kc8 = t & 7;
    const int nr = t >> 3;
    short8 v0, v1;
#pragma unroll
    for (int j = 0; j < 8; j++) {
      const int rowj = kc8 * 8 + j;
      const int swj = ((rowj >> 3) & 7) * 8;
      v0[j] = (short)tile[rowj][nr ^ swj];
      v1[j] = (short)tile[rowj][(nr + 32) ^ swj];
    }
    *(short8*)&d[(size_t)(n0 + nr) * K + k0 + kc8 * 8] = v0;
    *(short8*)&d[(size_t)(n0 + nr + 32) * K + k0 + kc8 * 8] = v1;
  }
}

// ---------------------------------------------------------------------------
// Fused QKV projection: qkv[m][n0..] = hs[m][k] * {Wq|Wk|Wv}[k][n].
// Tile 64(M) x 128(N), BK=32, grid (48,16) = 768 blocks.
// Q/K regions: split-precision (3 MFMA passes) when inputs fp32; V: 1 pass.
__global__ __launch_bounds__(256)
void gemm_qkv_kernel(const void* __restrict__ hsv, const void* __restrict__ Wqv,
                     const void* __restrict__ Wkv, const void* __restrict__ Wvv,
                     float* __restrict__ C, const ushort_t* __restrict__ msk) {
  const bool ibf = (msk[1] != 0);
  const int n0 = blockIdx.x * 128;
  const int m0 = blockIdx.y * 64;
  const void* Bv;
  int Nb, cb;
  bool wantSplit;
  if (n0 < 4096)      { Bv = Wqv; Nb = 4096; cb = n0;        wantSplit = true; }
  else if (n0 < 5120) { Bv = Wkv; Nb = 1024; cb = n0 - 4096; wantSplit = true; }
  else                { Bv = Wvv; Nb = 1024; cb = n0 - 5120; wantSplit = false; }
  const bool doSplit = wantSplit && !ibf;

  __shared__ alignas(16) bf16 sAh[64 * 32];
  __shared__ alignas(16) bf16 sAl[64 * 32];
  __shared__ alignas(16) bf16 sBh[128 * 32];   // swizzled [n][k]
  __shared__ alignas(16) bf16 sBl[128 * 32];

  const int t = threadIdx.x, lane = t & 63, wave = t >> 6;
  const int wm = (wave >> 1) * 32, wn = (wave & 1) * 64;
  const int mrow = lane & 15, kq = (lane >> 4) * 8;
  const int r0 = t >> 2, o0 = (t & 3) * 8;    // A staging: 64 rows x 32 k
  const int bk2 = (t >> 4) * 2;               // B staging: k pair
  const int bn8 = (t & 15) * 8;               // B staging: n group
  f32x4 acc[2][4];
#pragma unroll
  for (int i = 0; i < 2; i++)
#pragma unroll
    for (int j = 0; j < 4; j++) acc[i][j] = (f32x4){0.f, 0.f, 0.f, 0.f};

  for (int kk = 0; kk < DM; kk += 32) {
    short8 ah, al, bh0, bl0, bh1, bl1;
    if (ibf) {
      const bf16* A = (const bf16*)hsv;
      const bf16* B = (const bf16*)Bv;
      ah = *(const short8*)&A[(size_t)(m0 + r0) * DM + kk + o0];
      bh0 = *(const short8*)&B[(size_t)(kk + bk2) * Nb + cb + bn8];
      bh1 = *(const short8*)&B[(size_t)(kk + bk2 + 1) * Nb + cb + bn8];
    } else {
      const float* A = (const float*)hsv;
      const float* B = (const float*)Bv;
      split8(&A[(size_t)(m0 + r0) * DM + kk + o0], ah, al);
      if (doSplit) {
        split8(&B[(size_t)(kk + bk2) * Nb + cb + bn8], bh0, bl0);
        split8(&B[(size_t)(kk + bk2 + 1) * Nb + cb + bn8], bh1, bl1);
      } else {
        bh0 = cvt8(&B[(size_t)(kk + bk2) * Nb + cb + bn8]);
        bh1 = cvt8(&B[(size_t)(kk + bk2 + 1) * Nb + cb + bn8]);
      }
    }
    __syncthreads();
    *(short8*)&sAh[r0 * 32 + o0] = ah;
    if (doSplit) *(short8*)&sAl[r0 * 32 + o0] = al;
#pragma unroll
    for (int i = 0; i < 8; i++) {
      unsigned pv = (unsigned)(unsigned short)bh0[i] |
                    ((unsigned)(unsigned short)bh1[i] << 16);
      *(unsigned*)&sBh[bswz(bn8 + i, bk2)] = pv;
    }
    if (doSplit) {
#pragma unroll
      for (int i = 0; i < 8; i++) {
        unsigned pv = (unsigned)(unsigned short)bl0[i] |
                      ((unsigned)(unsigned short)bl1[i] << 16);
        *(unsigned*)&sBl[bswz(bn8 + i, bk2)] = pv;
      }
    }
    __syncthreads();
    short8 afh[2], bfh[4];
#pragma unroll
    for (int i = 0; i < 2; i++)
      afh[i] = *(const short8*)&sAh[(wm + i * 16 + mrow) * 32 + kq];
#pragma unroll
    for (int j = 0; j < 4; j++)
      bfh[j] = *(const short8*)&sBh[bswz(wn + j * 16 + mrow, kq)];
#pragma unroll
    for (int i = 0; i < 2; i++)
#pragma unroll
      for (int j = 0; j < 4; j++)
        acc[i][j] = __builtin_amdgcn_mfma_f32_16x16x32_bf16(afh[i], bfh[j], acc[i][j], 0, 0, 0);
    if (doSplit) {
      short8 afl[2], bfl[4];
#pragma unroll
      for (int i = 0; i < 2; i++)
        afl[i] = *(const short8*)&sAl[(wm + i * 16 + mrow) * 32 + kq];
#pragma unroll
      for (int j = 0; j < 4; j++)
        bfl[j] = *(const short8*)&sBl[bswz(wn + j * 16 + mrow, kq)];
#pragma unroll
      for (int i = 0; i < 2; i++)
#pragma unroll
        for (int j = 0; j < 4; j++) {
          acc[i][j] = __builtin_amdgcn_mfma_f32_16x16x32_bf16(afh[i], bfl[j], acc[i][j], 0, 0, 0);
          acc[i][j] = __builtin_amdgcn_mfma_f32_16x16x32_bf16(afl[i], bfh[j], acc[i][j], 0, 0, 0);
        }
    }
  }
  const int rq = (lane >> 4) * 4, cn = lane & 15;
#pragma unroll
  for (int i = 0; i < 2; i++)
#pragma unroll
    for (int r = 0; r < 4; r++) {
      const size_t rowi = (size_t)(m0 + wm + i * 16 + rq + r);
#pragma unroll
      for (int j = 0; j < 4; j++)
        C[rowi * 6144 + (n0 + wn + j * 16 + cn)] = acc[i][j][r];
    }
}

// ---------------------------------------------------------------------------
// Wo GEMM: out[m][n] = ao[m][k](bf16) * Wo[k][n]. Tile 64x128, grid (32,16).
__global__ __launch_bounds__(256)
void gemm_wo_kernel(const bf16* __restrict__ A, const void* __restrict__ Bv,
                    void* __restrict__ Cv, const ushort_t* __restrict__ msk) {
  const bool ibf = (msk[1] != 0);
  __shared__ alignas(16) bf16 sA[64 * 32];
  __shared__ alignas(16) bf16 sB[128 * 32];   // swizzled [n][k]
  const int n0 = blockIdx.x * 128;
  const int m0 = blockIdx.y * 64;
  const int t = threadIdx.x, lane = t & 63, wave = t >> 6;
  const int wm = (wave >> 1) * 32, wn = (wave & 1) * 64;
  const int mrow = lane & 15, kq = (lane >> 4) * 8;
  const int r0 = t >> 2, o0 = (t & 3) * 8;
  const int bk2 = (t >> 4) * 2;
  const int bn8 = (t & 15) * 8;
  f32x4 acc[2][4];
#pragma unroll
  for (int i = 0; i < 2; i++)
#pragma unroll
    for (int j = 0; j < 4; j++) acc[i][j] = (f32x4){0.f, 0.f, 0.f, 0.f};

  for (int kk = 0; kk < DM; kk += 32) {
    short8 av = *(const short8*)&A[(size_t)(m0 + r0) * DM + kk + o0];
    short8 bv0, bv1;
    if (ibf) {
      const bf16* B = (const bf16*)Bv;
      bv0 = *(const short8*)&B[(size_t)(kk + bk2) * DM + n0 + bn8];
      bv1 = *(const short8*)&B[(size_t)(kk + bk2 + 1) * DM + n0 + bn8];
    } else {
      const float* B = (const float*)Bv;
      bv0 = cvt8(&B[(size_t)(kk + bk2) * DM + n0 + bn8]);
      bv1 = cvt8(&B[(size_t)(kk + bk2 + 1) * DM + n0 + bn8]);
    }
    __syncthreads();
    *(short8*)&sA[r0 * 32 + o0] = av;
#pragma unroll
    for (int i = 0; i < 8; i++) {
      unsigned pv = (unsigned)(unsigned short)bv0[i] |
                    ((unsigned)(unsigned short)bv1[i] << 16);
      *(unsigned*)&sB[bswz(bn8 + i, bk2)] = pv;
    }
    __syncthreads();
    short8 af[2], bfr[4];
#pragma unroll
    for (int i = 0; i < 2; i++)
      af[i] = *(const short8*)&sA[(wm + i * 16 + mrow) * 32 + kq];
#pragma unroll
    for (int j = 0; j < 4; j++)
      bfr[j] = *(const short8*)&sB[bswz(wn + j * 16 + mrow, kq)];
#pragma unroll
    for (int i = 0; i < 2; i++)
#pragma unroll
      for (int j = 0; j < 4; j++)
        acc[i][j] = __builtin_amdgcn_mfma_f32_16x16x32_bf16(af[i], bfr[j], acc[i][j], 0, 0, 0);
  }
  const int rq = (lane >> 4) * 4, cn = lane & 15;
#pragma unroll
  for (int i = 0; i < 2; i++)
#pragma unroll
    for (int r = 0; r < 4; r++) {
      const size_t rowi = (size_t)(m0 + wm + i * 16 + rq + r);
#pragma unroll
      for (int j = 0; j < 4; j++) {
        const size_t idx = rowi * DM + (n0 + wn + j * 16 + cn);
        if (ibf)
          ((bf16*)Cv)[idx] = __float2bfloat16(acc[i][j][r]);
        else
          ((float*)Cv)[idx] = acc[i][j][r];
      }
    }
}

// ---------------------------------------------------------------------------
// RoPE for q + gq quantization. block=(128 threads)=one (h,pos).
__global__ __launch_bounds__(128)
void rope_q_gq_kernel(const float* __restrict__ qkv, const int* __restrict__ sc,
                      bf16* __restrict__ qr, float* __restrict__ gq) {
  const int pos = blockIdx.x, h = blockIdx.y, d = threadIdx.x;
  __shared__ float sv[HD], sr[HD];
  __shared__ float smn, smx;
  float v = qkv[(size_t)pos * 6144 + h * HD + d];
  sv[d] = v;
  __syncthreads();
  const int fi = d & 63;
  float inv = (float)(1.0 / pow(10000.0, (double)fi * (1.0 / 64.0)));
  float ang = (float)pos * inv;
  float c = cosf(ang), s = sinf(ang);
  float rot = (d < 64) ? -sv[d + 64] : sv[d - 64];
  float r = v * c + rot * s;
  sr[d] = r;
  qr[((size_t)h * QL + pos) * HD + d] = __float2bfloat16(r);
  __syncthreads();
  if (d == 0) {
    float mn = 3.4e38f, mx = -3.4e38f;
    for (int j = 0; j < OUTL; j++) {
      float g = sr[sc[h * HD + j]];
      mn = fminf(mn, g);
      mx = fmaxf(mx, g);
    }
    smn = mn; smx = mx;
  }
  __syncthreads();
  if (d < OUTL) {
    float g = sr[sc[h * HD + d]];
    float rng = smx - smn;
    if (rng == 0.f) rng = 1.f;
    float scale = 15.0f / rng;
    float qv = rintf((g - smn) * scale);
    qv = fminf(fmaxf(qv, 0.f), 15.f);
    gq[((size_t)h * QL + pos) * OUTL + d] = qv / scale + smn;
  }
}

// RoPE for k + gk quantization (per query-head) + v row cast.
__global__ __launch_bounds__(128)
void rope_k_gk_kernel(const float* __restrict__ qkv, const int* __restrict__ sc,
                      bf16* __restrict__ kr, bf16* __restrict__ vrow,
                      float* __restrict__ gk) {
  const int pos = blockIdx.x, kvh = blockIdx.y, d = threadIdx.x;
  __shared__ float sv[HD], sr[HD];
  __shared__ float smn[GRP], smx[GRP];
  float kv = qkv[(size_t)pos * 6144 + DM + kvh * HD + d];
  float vv = qkv[(size_t)pos * 6144 + DM + NKV * HD + kvh * HD + d];
  sv[d] = kv;
  __syncthreads();
  const int fi = d & 63;
  float inv = (float)(1.0 / pow(10000.0, (double)fi * (1.0 / 64.0)));
  float ang = (float)pos * inv;
  float c = cosf(ang), s = sinf(ang);
  float rot = (d < 64) ? -sv[d + 64] : sv[d - 64];
  float r = kv * c + rot * s;
  sr[d] = r;
  kr[((size_t)kvh * QL + pos) * HD + d] = __float2bfloat16(r);
  vrow[((size_t)kvh * QL + pos) * HD + d] = __float2bfloat16(vv);
  __syncthreads();
  if (d < 64 && (d & 15) == 0) {
    const int g = d >> 4;
    const int h = kvh * GRP + g;
    float mn = 3.4e38f, mx = -3.4e38f;
    for (int j = 0; j < OUTL; j++) {
      float x = sr[sc[h * HD + j]];
      mn = fminf(mn, x);
      mx = fmaxf(mx, x);
    }
    smn[g] = mn; smx[g] = mx;
  }
  __syncthreads();
  if (d < 64) {
    const int g = d >> 4, j = d & 15;
    const int h = kvh * GRP + g;
    float x = sr[sc[h * HD + j]];
    float rng = smx[g] - smn[g];
    if (rng == 0.f) rng = 1.f;
    float scale = 15.0f / rng;
    float qv = rintf((x - smn[g]) * scale);
    qv = fminf(fmaxf(qv, 0.f), 15.f);
    gk[((size_t)h * QL + pos) * OUTL + j] = qv / scale + smn[g];
  }
}

// ---------------------------------------------------------------------------
// Fused attention: one block = (head h, 8 queries). 256 threads = 4 waves.
__global__ __launch_bounds__(256)
void attn_kernel(const bf16* __restrict__ qr, const bf16* __restrict__ kr,
                 const bf16* __restrict__ vT, const float* __restrict__ gq,
                 const float* __restrict__ gk, bf16* __restrict__ ao) {
  const int h = blockIdx.y;
  const int q0 = blockIdx.x * 8;
  const int kvh = h >> 2;
  const int t = threadIdx.x;
  const int lane = t & 63, wave = t >> 6;
  const int mrow = lane & 15, kq = (lane >> 4) * 8;

  __shared__ alignas(16) bf16 sQ[16][HD];
  __shared__ float sGq[8][OUTL];
  __shared__ alignas(16) float sBuf[8][QL];
  __shared__ float sL[8];

  {
    const int r = t >> 4, c = (t & 15) * 8;
    short8 z = {0, 0, 0, 0, 0, 0, 0, 0};
    if (r < 8)
      *(short8*)&sQ[r][c] = *(const short8*)&qr[((size_t)h * QL + q0 + r) * HD + c];
    else
      *(short8*)&sQ[r][c] = z;
    if (t < 128)
      sGq[t >> 4][t & 15] = gq[((size_t)h * QL + q0 + (t >> 4)) * OUTL + (t & 15)];
  }
  __syncthreads();

  // ---- gattn (fp32, exact path for selection)
  for (int kk = t; kk < QL; kk += 256) {
    const float* gkp = &gk[((size_t)h * QL + kk) * OUTL];
    float gv[OUTL];
#pragma unroll
    for (int j = 0; j < OUTL; j++) gv[j] = gkp[j];
#pragma unroll
    for (int r = 0; r < 8; r++) {
      float s = 0.f;
#pragma unroll
      for (int j = 0; j < OUTL; j++) s += sGq[r][j] * gv[j];
      sBuf[r][kk] = (kk <= q0 + r) ? s * 0.25f : MNEG;
    }
  }
  __syncthreads();

  // ---- exact top-256 selection per row (stable-tie semantics)
  const int row = t >> 5, j32 = t & 31;
  unsigned sel;
  {
    unsigned uv[32];
#pragma unroll
    for (int kk = 0; kk < 32; kk++) uv[kk] = mapf(sBuf[row][j32 * 32 + kk]);
    unsigned T = 0u;
    for (int b = 31; b >= 0; b--) {
      unsigned Tc = T | (1u << b);
      int c = 0;
#pragma unroll
      for (int kk = 0; kk < 32; kk++) c += (uv[kk] >= Tc) ? 1 : 0;
      c += __shfl_xor(c, 1, 32);
      c += __shfl_xor(c, 2, 32);
      c += __shfl_xor(c, 4, 32);
      c += __shfl_xor(c, 8, 32);
      c += __shfl_xor(c, 16, 32);
      if (c >= HC) T = Tc;
    }
    unsigned gtm = 0u, eqm = 0u;
    int cgt = 0;
#pragma unroll
    for (int kk = 0; kk < 32; kk++) {
      unsigned u = uv[kk];
      if (u > T) { gtm |= (1u << kk); cgt++; }
      else if (u == T) eqm |= (1u << kk);
    }
    int cg = cgt;
    cg += __shfl_xor(cg, 1, 32);
    cg += __shfl_xor(cg, 2, 32);
    cg += __shfl_xor(cg, 4, 32);
    cg += __shfl_xor(cg, 8, 32);
    cg += __shfl_xor(cg, 16, 32);
    const int needEq = HC - cg;
    int eqc = __popc(eqm);
    int pre = eqc;
    for (int dlt = 1; dlt < 32; dlt <<= 1) {
      int o = __shfl_up(pre, dlt, 32);
      if (j32 >= dlt) pre += o;
    }
    pre -= eqc;
    int take = needEq - pre;
    unsigned mm = eqm;
    sel = gtm;
    for (int i = 0; i < take && mm != 0u; i++) {
      unsigned b = mm & (0u - mm);
      sel |= b;
      mm ^= b;
    }
  }
  __syncthreads();

  // ---- QK^T via MFMA (causal mask applied on store)
  {
    short8 aq[4];
#pragma unroll
    for (int kb = 0; kb < 4; kb++)
      aq[kb] = *(const short8*)&sQ[mrow][kb * 32 + kq];
    const bf16* krh = &kr[(size_t)kvh * QL * HD];
    for (int nt = wave; nt < 64; nt += 4) {
      const int kb0 = nt * 16;
      f32x4 acc = {0.f, 0.f, 0.f, 0.f};
#pragma unroll
      for (int kb = 0; kb < 4; kb++) {
        short8 bfr = *(const short8*)&krh[(size_t)(kb0 + mrow) * HD + kb * 32 + kq];
        acc = __builtin_amdgcn_mfma_f32_16x16x32_bf16(aq[kb], bfr, acc, 0, 0, 0);
      }
      const int key = kb0 + mrow;
#pragma unroll
      for (int r = 0; r < 4; r++) {
        const int m = (lane >> 4) * 4 + r;
        if (m < 8) {
          float v = acc[r] * 0.08838834764831845f;  // 1/sqrt(128)
          sBuf[m][key] = (key <= q0 + m) ? v : MNEG;
        }
      }
    }
  }
  __syncthreads();

  // ---- masked softmax; write p as bf16 overlay at sBuf base
  {
    float av[32];
    float mx = MNEG;
#pragma unroll
    for (int kk = 0; kk < 32; kk++) {
      av[kk] = sBuf[row][j32 * 32 + kk];
      if (sel & (1u << kk)) mx = fmaxf(mx, av[kk]);
    }
    mx = fmaxf(mx, __shfl_xor(mx, 1, 32));
    mx = fmaxf(mx, __shfl_xor(mx, 2, 32));
    mx = fmaxf(mx, __shfl_xor(mx, 4, 32));
    mx = fmaxf(mx, __shfl_xor(mx, 8, 32));
    mx = fmaxf(mx, __shfl_xor(mx, 16, 32));
    float ls = 0.f;
#pragma unroll
    for (int kk = 0; kk < 32; kk++) {
      float p = 0.f;
      if (sel & (1u << kk)) {
        float e = av[kk] - mx;
        p = (e < -80.f) ? 0.f : expf(e);
        ls += p;
      }
      av[kk] = p;
    }
    ls += __shfl_xor(ls, 1, 32);
    ls += __shfl_xor(ls, 2, 32);
    ls += __shfl_xor(ls, 4, 32);
    ls += __shfl_xor(ls, 8, 32);
    ls += __shfl_xor(ls, 16, 32);
    if (j32 == 0) sL[row] = ls;
    __syncthreads();
    bf16* P = (bf16*)&sBuf[0][0];
#pragma unroll
    for (int kk = 0; kk < 32; kk++)
      P[(size_t)row * QL + j32 * 32 + kk] = __float2bfloat16(av[kk]);
    short8 z = {0, 0, 0, 0, 0, 0, 0, 0};
    short8* Pz = (short8*)&sBuf[4][0];   // == &P[8*QL]
#pragma unroll
    for (int i = 0; i < 4; i++) Pz[t * 4 + i] = z;
  }
  __syncthreads();

  // ---- PV via MFMA (dense over 1024 keys; unselected p == 0)
  {
    const bf16* Pb = (const bf16*)&sBuf[0][0];
    const bf16* vTh = &vT[(size_t)kvh * HD * QL];
    for (int dt = wave; dt < 8; dt += 4) {
      const int d0 = dt * 16;
      f32x4 acc = {0.f, 0.f, 0.f, 0.f};
      for (int kb = 0; kb < 32; kb++) {
        short8 af = *(const short8*)&Pb[(size_t)mrow * QL + kb * 32 + kq];
        short8 bfr = *(const short8*)&vTh[(size_t)(d0 + mrow) * QL + kb * 32 + kq];
        acc = __builtin_amdgcn_mfma_f32_16x16x32_bf16(af, bfr, acc, 0, 0, 0);
      }
#pragma unroll
      for (int r = 0; r < 4; r++) {
        const int m = (lane >> 4) * 4 + r;
        if (m < 8) {
          float outv = acc[r] / sL[m];
          ao[(size_t)(q0 + m) * DM + h * HD + d0 + mrow] = __float2bfloat16(outv);
        }
      }
    }
  }
}

// ---------------------------------------------------------------------------
extern "C" void kernel_launch(void* const* d_in, const int* in_sizes, int n_in,
                              void* d_out, int out_size, void* d_ws, size_t ws_size,
                              hipStream_t stream) {
  (void)in_sizes; (void)n_in; (void)out_size; (void)ws_size;
  const void* hs = d_in[0];
  const ushort_t* msk = (const ushort_t*)d_in[1];  // dtype discriminator
  const void* Wq = d_in[3];
  const void* Wk = d_in[4];
  const void* Wv = d_in[5];
  const void* Wo = d_in[6];
  const int* sc = (const int*)d_in[7];

  char* ws = (char*)d_ws;
  size_t off = 0;
  auto alloc = [&](size_t bytes) {
    char* p = ws + off;
    off += (bytes + 255) & ~(size_t)255;
    return p;
  };
  float* qkv = (float*)alloc((size_t)QL * 6144 * 4);   // 25.2 MB
  bf16* ao = (bf16*)qkv;                               // aliases dead qkv
  bf16* qr = (bf16*)alloc((size_t)NH * QL * HD * 2);
  bf16* kr = (bf16*)alloc((size_t)NKV * QL * HD * 2);
  bf16* vrow = (bf16*)alloc((size_t)NKV * QL * HD * 2);
  bf16* vT = (bf16*)alloc((size_t)NKV * HD * QL * 2);
  float* gq = (float*)alloc((size_t)NH * QL * OUTL * 4);
  float* gk = (float*)alloc((size_t)NH * QL * OUTL * 4);
  // total ~42 MB

  // 1. fused QKV projection (768 blocks, 3/CU)
  gemm_qkv_kernel<<<dim3(48, 16), 256, 0, stream>>>(hs, Wq, Wk, Wv, qkv, msk);

  // 2. RoPE + quantized-label prep
  rope_q_gq_kernel<<<dim3(QL, NH), 128, 0, stream>>>(qkv, sc, qr, gq);
  rope_k_gk_kernel<<<dim3(QL, NKV), 128, 0, stream>>>(qkv, sc, kr, vrow, gk);
  transpose_bf16_kernel<<<dim3(2, 16, NKV), 256, 0, stream>>>(
      vrow, vT, QL, HD, (long long)(QL * HD), (long long)(HD * QL));

  // 3. fused attention (writes ao over dead qkv region)
  attn_kernel<<<dim3(QL / 8, NH), 256, 0, stream>>>(qr, kr, vT, gq, gk, ao);

  // 4. output projection (512 blocks, 2/CU; out dtype follows input dtype)
  gemm_wo_kernel<<<dim3(32, 16), 256, 0, stream>>>(ao, Wo, d_out, msk);
}